// Round 16
// baseline (254.651 us; speedup 1.0000x reference)
//
#include <hip/hip_runtime.h>
#include <hip/hip_bf16.h>
#include <stdint.h>

// Problem constants
#define D_ 1024
#define H_ 16
#define DH_ 64
#define F_ 4096
#define B_ 4
#define L_ 2048
#define MTOK 8192   // B_*L_

typedef __attribute__((ext_vector_type(8))) short bf16x8;
typedef __attribute__((ext_vector_type(4))) float f32x4;

__device__ __forceinline__ short f2bf(float f) {
  uint32_t u = __float_as_uint(f);
  uint32_t r = (u + 0x7FFFu + ((u >> 16) & 1u)) >> 16;
  return (short)(uint16_t)r;
}
__device__ __forceinline__ float bf2f(short s) {
  return __uint_as_float(((uint32_t)(uint16_t)s) << 16);
}

__device__ __forceinline__ void gload_lds16(const short* g, short* l) {
  __builtin_amdgcn_global_load_lds(
      (const __attribute__((address_space(1))) void*)g,
      (__attribute__((address_space(3))) void*)l,
      16, 0, 0);
}

#define FENCE asm volatile("" ::: "memory")
#define BARX  do { FENCE; __builtin_amdgcn_s_barrier(); FENCE; } while (0)
#define PRIO1 __builtin_amdgcn_s_setprio(1)
#define PRIO0 __builtin_amdgcn_s_setprio(0)

// ---------------- ALL f32->bf16 conversions in ONE launch ----------------
__global__ void __launch_bounds__(256) convert_all(
    const float* __restrict__ Wq, const float* __restrict__ Wk,
    const float* __restrict__ Wv, const float* __restrict__ Wo,
    const float* __restrict__ W1, const float* __restrict__ W2,
    const float* __restrict__ inputs,
    short* __restrict__ wqk, short* __restrict__ wv, short* __restrict__ wo,
    short* __restrict__ w1, short* __restrict__ w2, short* __restrict__ in_bf) {
  long i = ((long)blockIdx.x * 256 + threadIdx.x) * 4;
  const float* src; short* dst; long off; float scale = 1.0f;
  if (i < 65536L)        { src = Wq + 960L * 1024; dst = wqk;         off = i;            scale = 0.125f; }
  else if (i < 131072L)  { src = Wk + 960L * 1024; dst = wqk + 65536; off = i - 65536L;   }
  else if (i < 1179648L) { src = Wv;     dst = wv;    off = i - 131072L;   }
  else if (i < 2228224L) { src = Wo;     dst = wo;    off = i - 1179648L;  }
  else if (i < 6422528L) { src = W1;     dst = w1;    off = i - 2228224L;  }
  else if (i < 10616832L){ src = W2;     dst = w2;    off = i - 6422528L;  }
  else                   { src = inputs; dst = in_bf; off = i - 10616832L; }
  float4 f = *(const float4*)(src + off);
  short4 o4;
  o4.x = f2bf(f.x * scale); o4.y = f2bf(f.y * scale);
  o4.z = f2bf(f.z * scale); o4.w = f2bf(f.w * scale);
  *(short4*)(dst + off) = o4;
}

// ---------------- 1024x1024 bf16 transpose (for Wv^T) ----------------
__global__ void __launch_bounds__(256) transpose_bf16_1k(
    const short* __restrict__ src, short* __restrict__ dst) {
  __shared__ short t[64][65];
  const int bx = blockIdx.x, by = blockIdx.y;
  const int lr = threadIdx.x >> 4;          // 0..15
  const int lc = (threadIdx.x & 15) * 4;    // 0..60
#pragma unroll
  for (int rr = 0; rr < 4; rr++) {
    int r = lr * 4 + rr;
    short4 v = *(const short4*)&src[(long)(by * 64 + r) * 1024 + bx * 64 + lc];
    t[r][lc] = v.x; t[r][lc + 1] = v.y; t[r][lc + 2] = v.z; t[r][lc + 3] = v.w;
  }
  __syncthreads();
#pragma unroll
  for (int rr = 0; rr < 4; rr++) {
    int r = lr * 4 + rr;                    // source col index
    short4 v;
    v.x = t[lc + 0][r]; v.y = t[lc + 1][r];
    v.z = t[lc + 2][r]; v.w = t[lc + 3][r];
    *(short4*)&dst[(long)(bx * 64 + r) * 1024 + by * 64 + lc] = v;
  }
}

// =====================================================================
// gemm8p: R12/R15's proven best — 16x16x32 MFMA, 2-barrier ITER2 ledger,
// T2 both-sides swizzle (r&7), T1 XCD swizzle, LDS-staged 128B epilogue.
// Used for ctx and FFN-down.
// =====================================================================

#define RD_A(mh_, par_) do {                                                  \
  const short* bp = lds + (par_) * BUF + wm * ASLOT;                          \
  _Pragma("unroll")                                                           \
  for (int m2 = 0; m2 < MH; m2++) {                                           \
    const int r = ((mh_) * MH + m2) * 16 + l15;                               \
    _Pragma("unroll")                                                         \
    for (int ks = 0; ks < 2; ks++)                                            \
      aF[mh_][m2][ks] =                                                       \
          *(const bf16x8*)(bp + r * 64 + (((ks * 4 + l4) ^ (r & 7)) << 3));   \
  } } while (0)

#define RD_B(nh_, par_) do {                                                  \
  const short* bp = lds + (par_) * BUF + BM * 64 + (wn >> 1) * 8192;          \
  _Pragma("unroll")                                                           \
  for (int n2 = 0; n2 < 2; n2++) {                                            \
    const int r = (wn & 1) * 64 + ((nh_) * 2 + n2) * 16 + l15;                \
    _Pragma("unroll")                                                         \
    for (int ks = 0; ks < 2; ks++)                                            \
      bF[nh_][n2][ks] =                                                       \
          *(const bf16x8*)(bp + r * 64 + (((ks * 4 + l4) ^ (r & 7)) << 3));   \
  } } while (0)

#define QUAD(mh_, nh_) do {                                                   \
  _Pragma("unroll")                                                           \
  for (int ks = 0; ks < 2; ks++)                                              \
    _Pragma("unroll")                                                         \
    for (int m2 = 0; m2 < MH; m2++)                                           \
      _Pragma("unroll")                                                       \
      for (int n2 = 0; n2 < 2; n2++)                                          \
        acc[(mh_) * MH + m2][(nh_) * 2 + n2] =                                \
            __builtin_amdgcn_mfma_f32_16x16x32_bf16(                          \
                aF[mh_][m2][ks], bF[nh_][n2][ks],                             \
                acc[(mh_) * MH + m2][(nh_) * 2 + n2], 0, 0, 0);               \
} while (0)

#define ITER2(g_, par_, SN, SPP, GK) do {                                     \
  RD_B(0, par_); RD_A(0, par_); RD_B(1, par_);                                \
  if (SN) stA((g_) + 1, 1, (par_) ^ 1);                                       \
  PRIO1; QUAD(0, 0); QUAD(0, 1); PRIO0;                                       \
  BARX;                                                                       \
  RD_A(1, par_);                                                              \
  if (SPP) { stB((g_) + 2, 0, par_); stB((g_) + 2, 1, par_);                  \
             stA((g_) + 2, 0, par_); }                                        \
  PRIO1; QUAD(1, 0); QUAD(1, 1); PRIO0;                                       \
  if (GK == 1) asm volatile("s_waitcnt vmcnt(%0)" :: "i"(VG) : "memory");     \
  else if (GK == 2) asm volatile("s_waitcnt vmcnt(0)" ::: "memory");          \
  BARX;                                                                       \
} while (0)

template<int BMT, bool BIAS, bool RELU>
__global__ void __launch_bounds__(512, 2) gemm8p(
    const short* __restrict__ A, int lda,
    const short* __restrict__ Bm, int ldb,
    short* __restrict__ C, int ldc,
    const float* __restrict__ bias, int K) {
  constexpr int BM = BMT * 128;
  constexpr int MT = BMT * 4;
  constexpr int MH = MT / 2;
  constexpr int LA = BMT;
  constexpr int LB = 2;
  constexpr int ASLOT = (BM / 2) * 64;
  constexpr int BUF = BM * 64 + 16384;
  constexpr int VG = 2 * LB + LA;

  __shared__ __align__(16) short lds[2 * BUF];

  const int tid = threadIdx.x;
  const int lane = tid & 63;
  const int wave = tid >> 6;
  const int wm = wave >> 2, wn = wave & 3;
  const int l15 = lane & 15, l4 = lane >> 4;

  const int id = blockIdx.y * gridDim.x + blockIdx.x;
  const int per = (gridDim.x * gridDim.y) >> 3;
  const int swz = (id & 7) * per + (id >> 3);
  const int bn = swz % gridDim.x;
  const int bm = swz / gridDim.x;

  const short* Ab = A + (long)bm * BM * lda;
  const short* Bb = Bm + (long)bn * 256 * ldb;
  const int NTILE = K >> 6;

  const short* gA[2][LA]; short* dA[2][LA];
  const short* gB[2][LB]; short* dB[2][LB];
#pragma unroll
  for (int h = 0; h < 2; h++) {
#pragma unroll
    for (int l = 0; l < LA; l++) {
      int c = l * 512 + tid, r = c >> 3, cg = (c & 7) ^ (r & 7);
      gA[h][l] = Ab + (long)(h * (BM / 2) + r) * lda + cg * 8;
      dA[h][l] = lds + h * ASLOT + c * 8;
    }
#pragma unroll
    for (int l = 0; l < LB; l++) {
      int c = l * 512 + tid, r = c >> 3, cg = (c & 7) ^ (r & 7);
      gB[h][l] = Bb + (long)(h * 128 + r) * ldb + cg * 8;
      dB[h][l] = lds + BM * 64 + h * 8192 + c * 8;
    }
  }
  auto stA = [&](int t, int h, int par) {
#pragma unroll
    for (int l = 0; l < LA; l++)
      gload_lds16(gA[h][l] + (t << 6), dA[h][l] + par * BUF);
  };
  auto stB = [&](int t, int h, int par) {
#pragma unroll
    for (int l = 0; l < LB; l++)
      gload_lds16(gB[h][l] + (t << 6), dB[h][l] + par * BUF);
  };

  f32x4 acc[MT][4];
#pragma unroll
  for (int i = 0; i < MT; i++)
#pragma unroll
    for (int j = 0; j < 4; j++) acc[i][j] = (f32x4){0.f, 0.f, 0.f, 0.f};

  bf16x8 aF[2][MH][2];
  bf16x8 bF[2][2][2];

  stA(0, 0, 0); stA(0, 1, 0); stB(0, 0, 0); stB(0, 1, 0);
  stB(1, 0, 1); stB(1, 1, 1); stA(1, 0, 1);
  asm volatile("s_waitcnt vmcnt(%0)" :: "i"(VG) : "memory");
  BARX;

  for (int g = 0; g + 3 < NTILE; g += 2) {
    ITER2(g, 0, 1, 1, 1);
    ITER2(g + 1, 1, 1, 1, 1);
  }
  ITER2(NTILE - 2, 0, 1, 0, 2);
  ITER2(NTILE - 1, 1, 0, 0, 0);

  short* epi = lds + wave * 4608;
  const int col0 = bn * 256 + wn * 64;
  const int row0 = bm * BM + wm * (BM / 2);
  const int rg = lane >> 3, sg = lane & 7;
  float bb[4];
#pragma unroll
  for (int nt = 0; nt < 4; nt++)
    bb[nt] = BIAS ? bias[col0 + nt * 16 + l15] : 0.f;
#pragma unroll
  for (int h = 0; h < BMT; h++) {
#pragma unroll
    for (int m2 = 0; m2 < 4; m2++) {
#pragma unroll
      for (int nt = 0; nt < 4; nt++) {
#pragma unroll
        for (int r = 0; r < 4; r++) {
          float v = acc[h * 4 + m2][nt][r] + bb[nt];
          if (RELU) v = v > 0.f ? v : 0.f;
          epi[(m2 * 16 + l4 * 4 + r) * 72 + nt * 16 + l15] = f2bf(v);
        }
      }
    }
    FENCE;
#pragma unroll
    for (int it = 0; it < 8; it++) {
      const int rl = it * 8 + rg;
      bf16x8 vv = *(const bf16x8*)(epi + rl * 72 + sg * 8);
      *(bf16x8*)(C + (long)(row0 + h * 64 + rl) * ldc + col0 + sg * 8) = vv;
    }
    FENCE;
  }
}

// =====================================================================
// gemm_t3 (R16, FFN-up only): BM=128, BN=256, BK=32, 512 threads
// (8 waves 2Mx4N, per-wave 64x64), LDS = RING of 3 x 24KB = 72KB
// => 2 blocks/CU = 16 waves/CU of INDEPENDENT blocks (cross-block TLP:
// when one block sits at its barrier/gate, the other's waves feed the
// MFMA pipe — the 1-block/CU gemm8p exposes every stall CU-wide).
// One barrier per K-tile; stage tile g+2 into ring slot (g+2)%3 (its
// last reads completed before the end-of-(g-1) barrier); counted
// vmcnt(3) gate drains exactly tile g+1 (3 loads/thread/tile:
// outstanding = g+1's 3 + g+2's 3 -> drain to 3).
// BK=32 swizzle (verified vs BOTH conflict-grouping models, 2-way max):
// read slot = l4 ^ (r&3); stage source granule kg = (c&3) ^ (r&3) with
// linear LDS dest (rule 21: same involution both sides).
// =====================================================================
template<bool BIAS, bool RELU>
__global__ void __launch_bounds__(512, 4) gemm_t3(
    const short* __restrict__ A, int lda,
    const short* __restrict__ Bm, int ldb,
    short* __restrict__ C, int ldc,
    const float* __restrict__ bias, int K) {
  constexpr int ABUF = 4096;             // shorts: A 128x32
  constexpr int BUF  = 12288;            // shorts per ring slot (A+B)
  __shared__ __align__(16) short lds[3 * BUF];   // 72KB

  const int tid = threadIdx.x;
  const int lane = tid & 63;
  const int wave = tid >> 6;
  const int wm = wave >> 2, wn = wave & 3;
  const int l15 = lane & 15, l4 = lane >> 4;

  // T1: XCD-aware bijective swizzle (grid size is a multiple of 8)
  const int id = blockIdx.y * gridDim.x + blockIdx.x;
  const int per = (gridDim.x * gridDim.y) >> 3;
  const int swz = (id & 7) * per + (id >> 3);
  const int bn = swz % gridDim.x;
  const int bm = swz / gridDim.x;

  const short* Ab = A + (long)bm * 128 * lda;
  const short* Bb = Bm + (long)bn * 256 * ldb;
  const int NTILE = K >> 5;

  // staging: A 512 chunks (1/thread), B 1024 chunks (2/thread).
  // chunk c: row r = c>>2, physical slot s = c&3, logical granule
  // kg = s ^ (r&3) (source-side swizzle; LDS dest linear).
  const short* gA0; int dOfA;
  {
    int c = tid, r = c >> 2, kg = (c & 3) ^ (r & 3);
    gA0 = Ab + (long)r * lda + kg * 8;
    dOfA = c * 8;
  }
  const short* gB[2]; int dOfB[2];
#pragma unroll
  for (int l = 0; l < 2; l++) {
    int c = l * 512 + tid, r = c >> 2, kg = (c & 3) ^ (r & 3);
    gB[l] = Bb + (long)r * ldb + kg * 8;
    dOfB[l] = ABUF + c * 8;
  }
  auto stage = [&](int t, int pS) {
    const int k0 = t << 5;
    gload_lds16(gA0 + k0, lds + pS + dOfA);
#pragma unroll
    for (int l = 0; l < 2; l++) gload_lds16(gB[l] + k0, lds + pS + dOfB[l]);
  };

  // frag read offsets (shorts): frag t rows base+t*16+l15, slot l4^(r&3)
  int aOf[4], bOf[4];
#pragma unroll
  for (int t = 0; t < 4; t++) {
    int ra = wm * 64 + t * 16 + l15;
    int rb = wn * 64 + t * 16 + l15;
    aOf[t] = (ra * 4 + (l4 ^ (ra & 3))) * 8;
    bOf[t] = ABUF + (rb * 4 + (l4 ^ (rb & 3))) * 8;
  }

  f32x4 acc[4][4];
#pragma unroll
  for (int i = 0; i < 4; i++)
#pragma unroll
    for (int j = 0; j < 4; j++) acc[i][j] = (f32x4){0.f, 0.f, 0.f, 0.f};

  // prologue: tiles 0,1 into slots 0,1; drain tile0 (6 outstanding -> 3)
  stage(0, 0); stage(1, BUF);
  asm volatile("s_waitcnt vmcnt(3)" ::: "memory");
  BARX;

  int p0 = 0, p1 = BUF, p2 = 2 * BUF;
  for (int g = 0; g < NTILE; g++) {
    bf16x8 aF[4], bF[4];
#pragma unroll
    for (int t = 0; t < 4; t++) aF[t] = *(const bf16x8*)(lds + p0 + aOf[t]);
#pragma unroll
    for (int t = 0; t < 4; t++) bF[t] = *(const bf16x8*)(lds + p0 + bOf[t]);
    if (g + 2 < NTILE) stage(g + 2, p2);
    PRIO1;
#pragma unroll
    for (int mt = 0; mt < 4; mt++)
#pragma unroll
      for (int nt = 0; nt < 4; nt++)
        acc[mt][nt] = __builtin_amdgcn_mfma_f32_16x16x32_bf16(
            aF[mt], bF[nt], acc[mt][nt], 0, 0, 0);
    PRIO0;
    if (g + 2 < NTILE)
      asm volatile("s_waitcnt vmcnt(3)" ::: "memory");   // tile g+1 landed
    else if (g + 1 < NTILE)
      asm volatile("s_waitcnt vmcnt(0)" ::: "memory");
    BARX;
    int tmp = p0; p0 = p1; p1 = p2; p2 = tmp;
  }

  // epilogue: R12 pattern, per-wave 64x64 tile through LDS, 128B stores.
  short* epi = lds + wave * 4608;        // 64*72 shorts per wave (72KB/8w)
  const int col0 = bn * 256 + wn * 64;
  const int row0 = bm * 128 + wm * 64;
  const int rg = lane >> 3, sg = lane & 7;
  float bb[4];
#pragma unroll
  for (int nt = 0; nt < 4; nt++)
    bb[nt] = BIAS ? bias[col0 + nt * 16 + l15] : 0.f;
#pragma unroll
  for (int m2 = 0; m2 < 4; m2++) {
#pragma unroll
    for (int nt = 0; nt < 4; nt++) {
#pragma unroll
      for (int r = 0; r < 4; r++) {
        float v = acc[m2][nt][r] + bb[nt];
        if (RELU) v = v > 0.f ? v : 0.f;
        epi[(m2 * 16 + l4 * 4 + r) * 72 + nt * 16 + l15] = f2bf(v);
      }
    }
  }
  FENCE;
#pragma unroll
  for (int it = 0; it < 8; it++) {
    const int rl = it * 8 + rg;
    bf16x8 vv = *(const bf16x8*)(epi + rl * 72 + sg * 8);
    *(bf16x8*)(C + (long)(row0 + rl) * ldc + col0 + sg * 8) = vv;
  }
}

// ---------------- merged small GEMMs: qkh (blocks 0..63) + wf (64..127) ----
__global__ void __launch_bounds__(256) gemm_small(
    const short* __restrict__ in_bf, const short* __restrict__ wqk,
    short* __restrict__ qkh,
    const short* __restrict__ wo, const short* __restrict__ wvT,
    short* __restrict__ wf) {
  const short* A; const short* Bm; short* C;
  int ldc, bn, bm;
  const int bid = blockIdx.x;
  if (bid < 64) { A = in_bf; Bm = wqk; C = qkh; ldc = 128; bn = 0; bm = bid; }
  else { A = wo; Bm = wvT; C = wf; ldc = 1024; int b2 = bid - 64; bn = b2 & 7; bm = b2 >> 3; }
  const int lda = 1024, ldb = 1024, K = 1024;

  const short* Ab = A + (long)bm * 128 * lda;
  const short* Bb = Bm + (long)bn * 128 * ldb;

  __shared__ short lA[128 * 64];
  __shared__ short lB[128 * 64];

  const int tid = threadIdx.x;
  const int lane = tid & 63;
  const int wave = tid >> 6;
  const int wr = wave >> 1, wc = wave & 1;

  f32x4 acc[4][4];
#pragma unroll
  for (int i = 0; i < 4; i++)
#pragma unroll
    for (int j = 0; j < 4; j++) acc[i][j] = (f32x4){0.f, 0.f, 0.f, 0.f};

  for (int k0 = 0; k0 < K; k0 += 64) {
    __syncthreads();
#pragma unroll
    for (int i = 0; i < 4; i++) {
      int c = i * 256 + tid;
      int row = c >> 3;
      int col = (c & 7) * 8;
      gload_lds16(Ab + (long)row * lda + k0 + col, &lA[c * 8]);
      gload_lds16(Bb + (long)row * ldb + k0 + col, &lB[c * 8]);
    }
    __syncthreads();

#pragma unroll
    for (int ks = 0; ks < 2; ks++) {
      bf16x8 af[4], bfr[4];
#pragma unroll
      for (int t = 0; t < 4; t++) {
        af[t]  = *(const bf16x8*)&lA[(wr * 64 + t * 16 + (lane & 15)) * 64 + ks * 32 + (lane >> 4) * 8];
        bfr[t] = *(const bf16x8*)&lB[(wc * 64 + t * 16 + (lane & 15)) * 64 + ks * 32 + (lane >> 4) * 8];
      }
#pragma unroll
      for (int mt = 0; mt < 4; mt++)
#pragma unroll
        for (int nt = 0; nt < 4; nt++)
          acc[mt][nt] = __builtin_amdgcn_mfma_f32_16x16x32_bf16(af[mt], bfr[nt], acc[mt][nt], 0, 0, 0);
    }
  }

  const int col0 = bn * 128 + wc * 64;
  const int row0 = bm * 128 + wr * 64;
#pragma unroll
  for (int mt = 0; mt < 4; mt++) {
#pragma unroll
    for (int nt = 0; nt < 4; nt++) {
      int col = col0 + nt * 16 + (lane & 15);
      int rbase = row0 + mt * 16 + (lane >> 4) * 4;
#pragma unroll
      for (int r = 0; r < 4; r++)
        C[(long)(rbase + r) * ldc + col] = f2bf(acc[mt][nt][r]);
    }
  }
}

// =====================================================================
// Fused scores + softmax (+ /H), single-pass, S in registers.
// =====================================================================
__global__ void __launch_bounds__(512) fused_attn(
    const short* __restrict__ qkh, float* __restrict__ attn) {
  const int tid = threadIdx.x;
  const int lane = tid & 63;
  const int wave = tid >> 6;       // 0..7 (kv-eighth)
  const int l15 = lane & 15, l4 = lane >> 4;
  const int b = blockIdx.y;
  const int q0 = blockIdx.x * 16;
  const long base = (long)b * 2048;

  bf16x8 qf[2];
#pragma unroll
  for (int ks = 0; ks < 2; ks++)
    qf[ks] = *(const bf16x8*)&qkh[(base + q0 + l15) * 128 + ks * 32 + l4 * 8];

  const short* kb = qkh + (base + (long)wave * 256) * 128 + 64;

  f32x4 s[16];
#pragma unroll
  for (int kt = 0; kt < 16; kt++) {
    bf16x8 kf0 = *(const bf16x8*)&kb[(kt * 16 + l15) * 128 + l4 * 8];
    bf16x8 kf1 = *(const bf16x8*)&kb[(kt * 16 + l15) * 128 + 32 + l4 * 8];
    f32x4 a = (f32x4){0.f, 0.f, 0.f, 0.f};
    a = __builtin_amdgcn_mfma_f32_16x16x32_bf16(kf0, qf[0], a, 0, 0, 0);
    a = __builtin_amdgcn_mfma_f32_16x16x32_bf16(kf1, qf[1], a, 0, 0, 0);
    s[kt] = a;
  }

  float m = -1e30f;
#pragma unroll
  for (int kt = 0; kt < 16; kt++)
    m = fmaxf(m, fmaxf(fmaxf(s[kt][0], s[kt][1]), fmaxf(s[kt][2], s[kt][3])));
#pragma unroll
  for (int o = 16; o <= 32; o <<= 1) m = fmaxf(m, __shfl_xor(m, o, 64));

  float ss = 0.f;
#pragma unroll
  for (int kt = 0; kt < 16; kt++) {
    f32x4 e;
#pragma unroll
    for (int r = 0; r < 4; r++) e[r] = __expf(s[kt][r] - m);
    s[kt] = e;
    ss += (e[0] + e[1]) + (e[2] + e[3]);
  }
#pragma unroll
  for (int o = 16; o <= 32; o <<= 1) ss += __shfl_xor(ss, o, 64);

  __shared__ float lm[8][16], lsm[8][16];
  if (lane < 16) { lm[wave][l15] = m; lsm[wave][l15] = ss; }
  __syncthreads();
  float M = -1e30f;
#pragma unroll
  for (int w2 = 0; w2 < 8; w2++) M = fmaxf(M, lm[w2][l15]);
  float S = 0.f;
#pragma unroll
  for (int w2 = 0; w2 < 8; w2++) S += lsm[w2][l15] * __expf(lm[w2][l15] - M);
  const float f = __expf(m - M) / (S * 16.0f);   // includes the /H

  float* attb = attn + (base + q0 + l15) * 2048 + wave * 256 + l4 * 4;
#pragma unroll
  for (int kt = 0; kt < 16; kt++) {
    f32x4 p;
#pragma unroll
    for (int r = 0; r < 4; r++) p[r] = s[kt][r] * f;
    *(f32x4*)(attb + kt * 16) = p;
  }
}

// ---------------- fused residual + LayerNorm (f32 out) ----------------
__device__ __forceinline__ float wave_sum(float v) {
#pragma unroll
  for (int o = 32; o > 0; o >>= 1) v += __shfl_xor(v, o, 64);
  return v;
}

__global__ void __launch_bounds__(256) ln_fuse(
    const short* __restrict__ ctx, const short* __restrict__ ffn,
    const float* __restrict__ g, const float* __restrict__ bta,
    float* __restrict__ out) {
  const int tid = threadIdx.x;
  long base = (long)blockIdx.x * 1024 + tid * 4;
  short4 c4 = *(const short4*)(ctx + base);
  short4 f4 = *(const short4*)(ffn + base);
  float x0 = bf2f(c4.x) + bf2f(f4.x);
  float x1 = bf2f(c4.y) + bf2f(f4.y);
  float x2 = bf2f(c4.z) + bf2f(f4.z);
  float x3 = bf2f(c4.w) + bf2f(f4.w);

  float s = (x0 + x1) + (x2 + x3);
  float q = (x0 * x0 + x1 * x1) + (x2 * x2 + x3 * x3);
  __shared__ float rs[4], rq[4];
  s = wave_sum(s);
  q = wave_sum(q);
  if ((tid & 63) == 0) { rs[tid >> 6] = s; rq[tid >> 6] = q; }
  __syncthreads();
  float S = rs[0] + rs[1] + rs[2] + rs[3];
  float Q = rq[0] + rq[1] + rq[2] + rq[3];
  float mu = S * (1.0f / 1024.0f);
  float var = Q * (1.0f / 1024.0f) - mu * mu;
  float inv = rsqrtf(var + 1e-5f);

  float4 g4 = *(const float4*)(g + tid * 4);
  float4 b4 = *(const float4*)(bta + tid * 4);
  float4 o;
  o.x = (x0 - mu) * inv * g4.x + b4.x;
  o.y = (x1 - mu) * inv * g4.y + b4.y;
  o.z = (x2 - mu) * inv * g4.z + b4.z;
  o.w = (x3 - mu) * inv * g4.w + b4.w;
  *(float4*)(out + base) = o;
}

// ---------------- launch ----------------
extern "C" void kernel_launch(void* const* d_in, const int* in_sizes, int n_in,
                              void* d_out, int out_size, void* d_ws, size_t ws_size,
                              hipStream_t stream) {
  const float* inputs = (const float*)d_in[0];
  const float* Wq = (const float*)d_in[1];
  const float* Wk = (const float*)d_in[2];
  const float* Wv = (const float*)d_in[3];
  const float* Wo = (const float*)d_in[4];
  const float* W1 = (const float*)d_in[5];
  const float* b1 = (const float*)d_in[6];
  const float* W2 = (const float*)d_in[7];
  const float* b2 = (const float*)d_in[8];
  const float* ln_g = (const float*)d_in[9];
  const float* ln_b = (const float*)d_in[10];

  char* w = (char*)d_ws;
  short* in_bf = (short*)w;  w += (long)MTOK * D_ * 2;
  short* wqk   = (short*)w;  w += 128L * D_ * 2;
  short* wv    = (short*)w;  w += (long)D_ * D_ * 2;
  short* wo    = (short*)w;  w += (long)D_ * D_ * 2;
  short* w1    = (short*)w;  w += (long)F_ * D_ * 2;
  short* w2    = (short*)w;  w += (long)D_ * F_ * 2;
  short* qkh   = (short*)w;  w += (long)MTOK * 128 * 2;
  short* wvT   = (short*)w;  w += (long)D_ * D_ * 2;   // Wv^T (bf16)
  short* wf    = (short*)w;  w += (long)D_ * D_ * 2;   // Wf = Wo @ Wv (bf16)
  short* ctxbf = (short*)w;  w += (long)MTOK * D_ * 2;
  short* hbf   = (short*)w;  w += (long)MTOK * F_ * 2;
  short* ffnbf = (short*)w;  w += (long)MTOK * D_ * 2;

  float* out  = (float*)d_out;                 // [8192][1024]
  float* attn = out + (long)MTOK * D_;         // [4][2048][2048]

  // all conversions in one launch (wq slice pre-scaled by DH^-0.5)
  convert_all<<<dim3(18560), 256, 0, stream>>>(
      Wq, Wk, Wv, Wo, W1, W2, inputs, wqk, wv, wo, w1, w2, in_bf);

  // Wv^T, then merged small GEMMs: qkh = in @ wqk^T  and  wf = Wo @ Wv
  transpose_bf16_1k<<<dim3(16, 16), 256, 0, stream>>>(wv, wvT);
  gemm_small<<<dim3(128), 256, 0, stream>>>(in_bf, wqk, qkh, wo, wvT, wf);

  // attn = softmax(qH @ kH^T)/H  — single-pass fused
  fused_attn<<<dim3(128, 4), 512, 0, stream>>>(qkh, attn);
  // context = inputs @ Wf^T  (M=8192, N=1024, K=1024) — proven gemm8p
  gemm8p<1, false, false><<<dim3(4, 64), 512, 0, stream>>>(
      in_bf, D_, wf, D_, ctxbf, D_, nullptr, D_);
  // h = relu(ctx @ W1^T + b1) (M=8192, N=4096, K=1024) — NEW gemm_t3
  gemm_t3<true, true><<<dim3(16, 64), 512, 0, stream>>>(
      ctxbf, D_, w1, D_, hbf, F_, b1, D_);
  // ffn = h @ W2^T + b2       (M=8192, N=1024, K=4096) — proven gemm8p
  gemm8p<1, true, false><<<dim3(4, 64), 512, 0, stream>>>(
      hbf, F_, w2, F_, ffnbf, D_, b2, F_);
  // out = LN(ctx + ffn)
  ln_fuse<<<dim3(MTOK), 256, 0, stream>>>(ctxbf, ffnbf, ln_g, ln_b, out);
}

// Round 17
// 241.375 us; speedup vs baseline: 1.0550x; 1.0550x over previous
//
#include <hip/hip_runtime.h>
#include <hip/hip_bf16.h>
#include <stdint.h>

// Problem constants
#define D_ 1024
#define H_ 16
#define DH_ 64
#define F_ 4096
#define B_ 4
#define L_ 2048
#define MTOK 8192   // B_*L_

typedef __attribute__((ext_vector_type(8))) short bf16x8;
typedef __attribute__((ext_vector_type(4))) float f32x4;

__device__ __forceinline__ short f2bf(float f) {
  uint32_t u = __float_as_uint(f);
  uint32_t r = (u + 0x7FFFu + ((u >> 16) & 1u)) >> 16;
  return (short)(uint16_t)r;
}
__device__ __forceinline__ float bf2f(short s) {
  return __uint_as_float(((uint32_t)(uint16_t)s) << 16);
}

__device__ __forceinline__ void gload_lds16(const short* g, short* l) {
  __builtin_amdgcn_global_load_lds(
      (const __attribute__((address_space(1))) void*)g,
      (__attribute__((address_space(3))) void*)l,
      16, 0, 0);
}

#define FENCE asm volatile("" ::: "memory")
#define BARX  do { FENCE; __builtin_amdgcn_s_barrier(); FENCE; } while (0)
#define PRIO1 __builtin_amdgcn_s_setprio(1)
#define PRIO0 __builtin_amdgcn_s_setprio(0)

// ---------------- ALL f32->bf16 conversions in ONE launch ----------------
__global__ void __launch_bounds__(256) convert_all(
    const float* __restrict__ Wq, const float* __restrict__ Wk,
    const float* __restrict__ Wv, const float* __restrict__ Wo,
    const float* __restrict__ W1, const float* __restrict__ W2,
    const float* __restrict__ inputs,
    short* __restrict__ wqk, short* __restrict__ wv, short* __restrict__ wo,
    short* __restrict__ w1, short* __restrict__ w2, short* __restrict__ in_bf) {
  long i = ((long)blockIdx.x * 256 + threadIdx.x) * 4;
  const float* src; short* dst; long off; float scale = 1.0f;
  if (i < 65536L)        { src = Wq + 960L * 1024; dst = wqk;         off = i;            scale = 0.125f; }
  else if (i < 131072L)  { src = Wk + 960L * 1024; dst = wqk + 65536; off = i - 65536L;   }
  else if (i < 1179648L) { src = Wv;     dst = wv;    off = i - 131072L;   }
  else if (i < 2228224L) { src = Wo;     dst = wo;    off = i - 1179648L;  }
  else if (i < 6422528L) { src = W1;     dst = w1;    off = i - 2228224L;  }
  else if (i < 10616832L){ src = W2;     dst = w2;    off = i - 6422528L;  }
  else                   { src = inputs; dst = in_bf; off = i - 10616832L; }
  float4 f = *(const float4*)(src + off);
  short4 o4;
  o4.x = f2bf(f.x * scale); o4.y = f2bf(f.y * scale);
  o4.z = f2bf(f.z * scale); o4.w = f2bf(f.w * scale);
  *(short4*)(dst + off) = o4;
}

// ---------------- 1024x1024 bf16 transpose (for Wv^T) ----------------
__global__ void __launch_bounds__(256) transpose_bf16_1k(
    const short* __restrict__ src, short* __restrict__ dst) {
  __shared__ short t[64][65];
  const int bx = blockIdx.x, by = blockIdx.y;
  const int lr = threadIdx.x >> 4;          // 0..15
  const int lc = (threadIdx.x & 15) * 4;    // 0..60
#pragma unroll
  for (int rr = 0; rr < 4; rr++) {
    int r = lr * 4 + rr;
    short4 v = *(const short4*)&src[(long)(by * 64 + r) * 1024 + bx * 64 + lc];
    t[r][lc] = v.x; t[r][lc + 1] = v.y; t[r][lc + 2] = v.z; t[r][lc + 3] = v.w;
  }
  __syncthreads();
#pragma unroll
  for (int rr = 0; rr < 4; rr++) {
    int r = lr * 4 + rr;                    // source col index
    short4 v;
    v.x = t[lc + 0][r]; v.y = t[lc + 1][r];
    v.z = t[lc + 2][r]; v.w = t[lc + 3][r];
    *(short4*)&dst[(long)(bx * 64 + r) * 1024 + by * 64 + lc] = v;
  }
}

// =====================================================================
// gemm8p: R12/R15's proven best — 16x16x32 MFMA (measured faster than
// 32x32x16 here: 70.8 vs 80.5 µs FFN-up; 8 independent acc chains per
// QUAD), 2-barrier ITER2 counted-vmcnt ledger, T2 both-sides swizzle
// (r&7 — the 8-slot/row minimum; all BK=32 4-slot layouts measured
// ~8.5M conflicts across 3 swizzle designs), T1 XCD swizzle, and the
// LDS-staged 128B-contiguous epilogue (WRITE_SIZE 143->70 MB, -17.6 µs).
// =====================================================================

#define RD_A(mh_, par_) do {                                                  \
  const short* bp = lds + (par_) * BUF + wm * ASLOT;                          \
  _Pragma("unroll")                                                           \
  for (int m2 = 0; m2 < MH; m2++) {                                           \
    const int r = ((mh_) * MH + m2) * 16 + l15;                               \
    _Pragma("unroll")                                                         \
    for (int ks = 0; ks < 2; ks++)                                            \
      aF[mh_][m2][ks] =                                                       \
          *(const bf16x8*)(bp + r * 64 + (((ks * 4 + l4) ^ (r & 7)) << 3));   \
  } } while (0)

#define RD_B(nh_, par_) do {                                                  \
  const short* bp = lds + (par_) * BUF + BM * 64 + (wn >> 1) * 8192;          \
  _Pragma("unroll")                                                           \
  for (int n2 = 0; n2 < 2; n2++) {                                            \
    const int r = (wn & 1) * 64 + ((nh_) * 2 + n2) * 16 + l15;                \
    _Pragma("unroll")                                                         \
    for (int ks = 0; ks < 2; ks++)                                            \
      bF[nh_][n2][ks] =                                                       \
          *(const bf16x8*)(bp + r * 64 + (((ks * 4 + l4) ^ (r & 7)) << 3));   \
  } } while (0)

#define QUAD(mh_, nh_) do {                                                   \
  _Pragma("unroll")                                                           \
  for (int ks = 0; ks < 2; ks++)                                              \
    _Pragma("unroll")                                                         \
    for (int m2 = 0; m2 < MH; m2++)                                           \
      _Pragma("unroll")                                                       \
      for (int n2 = 0; n2 < 2; n2++)                                          \
        acc[(mh_) * MH + m2][(nh_) * 2 + n2] =                                \
            __builtin_amdgcn_mfma_f32_16x16x32_bf16(                          \
                aF[mh_][m2][ks], bF[nh_][n2][ks],                             \
                acc[(mh_) * MH + m2][(nh_) * 2 + n2], 0, 0, 0);               \
} while (0)

// par_ must be a literal 0/1. SN: stage A1(g+1); SPP: stage B0/B1/A0(g+2);
// GK: 1 = vmcnt(VG), 2 = vmcnt(0), 0 = none.
#define ITER2(g_, par_, SN, SPP, GK) do {                                     \
  /* phase 1: reads in consumption order; compiler inserts counted waits */   \
  RD_B(0, par_); RD_A(0, par_); RD_B(1, par_);                                \
  if (SN) stA((g_) + 1, 1, (par_) ^ 1);                                       \
  PRIO1; QUAD(0, 0); QUAD(0, 1); PRIO0;                                       \
  BARX;  /* mid-tile: phase1 reads consumed into regs in all waves */         \
  /* phase 2 */                                                               \
  RD_A(1, par_);                                                              \
  if (SPP) { stB((g_) + 2, 0, par_); stB((g_) + 2, 1, par_);                  \
             stA((g_) + 2, 0, par_); }                                        \
  PRIO1; QUAD(1, 0); QUAD(1, 1); PRIO0;                                       \
  if (GK == 1) asm volatile("s_waitcnt vmcnt(%0)" :: "i"(VG) : "memory");     \
  else if (GK == 2) asm volatile("s_waitcnt vmcnt(0)" ::: "memory");          \
  BARX;  /* tile boundary: next tile's buf published */                       \
} while (0)

template<int BMT, bool BIAS, bool RELU>
__global__ void __launch_bounds__(512, 2) gemm8p(
    const short* __restrict__ A, int lda,
    const short* __restrict__ Bm, int ldb,
    short* __restrict__ C, int ldc,
    const float* __restrict__ bias, int K) {
  constexpr int BM = BMT * 128;
  constexpr int MT = BMT * 4;            // M-frags per wave
  constexpr int MH = MT / 2;             // M-frags per quadrant
  constexpr int LA = BMT;                // per-thread loads per A-half
  constexpr int LB = 2;                  // per-thread loads per B-half
  constexpr int ASLOT = (BM / 2) * 64;   // shorts per A-half slot
  constexpr int BUF = BM * 64 + 16384;   // shorts per buffer (A + B)
  constexpr int VG = 2 * LB + LA;        // steady-state gate count

  __shared__ __align__(16) short lds[2 * BUF];

  const int tid = threadIdx.x;
  const int lane = tid & 63;
  const int wave = tid >> 6;
  const int wm = wave >> 2, wn = wave & 3;
  const int l15 = lane & 15, l4 = lane >> 4;

  // T1: XCD-aware bijective swizzle (grid size is a multiple of 8)
  const int id = blockIdx.y * gridDim.x + blockIdx.x;
  const int per = (gridDim.x * gridDim.y) >> 3;
  const int swz = (id & 7) * per + (id >> 3);
  const int bn = swz % gridDim.x;
  const int bm = swz / gridDim.x;

  const short* Ab = A + (long)bm * BM * lda;
  const short* Bb = Bm + (long)bn * 256 * ldb;
  const int NTILE = K >> 6;

  // Precomputed per-thread staging pointers: only (t<<6) is runtime.
  const short* gA[2][LA]; short* dA[2][LA];
  const short* gB[2][LB]; short* dB[2][LB];
#pragma unroll
  for (int h = 0; h < 2; h++) {
#pragma unroll
    for (int l = 0; l < LA; l++) {
      int c = l * 512 + tid, r = c >> 3, cg = (c & 7) ^ (r & 7);
      gA[h][l] = Ab + (long)(h * (BM / 2) + r) * lda + cg * 8;
      dA[h][l] = lds + h * ASLOT + c * 8;
    }
#pragma unroll
    for (int l = 0; l < LB; l++) {
      int c = l * 512 + tid, r = c >> 3, cg = (c & 7) ^ (r & 7);
      gB[h][l] = Bb + (long)(h * 128 + r) * ldb + cg * 8;
      dB[h][l] = lds + BM * 64 + h * 8192 + c * 8;
    }
  }
  auto stA = [&](int t, int h, int par) {
#pragma unroll
    for (int l = 0; l < LA; l++)
      gload_lds16(gA[h][l] + (t << 6), dA[h][l] + par * BUF);
  };
  auto stB = [&](int t, int h, int par) {
#pragma unroll
    for (int l = 0; l < LB; l++)
      gload_lds16(gB[h][l] + (t << 6), dB[h][l] + par * BUF);
  };

  f32x4 acc[MT][4];
#pragma unroll
  for (int i = 0; i < MT; i++)
#pragma unroll
    for (int j = 0; j < 4; j++) acc[i][j] = (f32x4){0.f, 0.f, 0.f, 0.f};

  bf16x8 aF[2][MH][2];   // [mh][m2][ks]
  bf16x8 bF[2][2][2];    // [nh][n2][ks]

  // prologue: tile0 fully; tile1 all but A1 (A1(t1) staged at tile0 ph1)
  stA(0, 0, 0); stA(0, 1, 0); stB(0, 0, 0); stB(0, 1, 0);
  stB(1, 0, 1); stB(1, 1, 1); stA(1, 0, 1);
  asm volatile("s_waitcnt vmcnt(%0)" :: "i"(VG) : "memory");  // tile0 landed
  BARX;

  for (int g = 0; g + 3 < NTILE; g += 2) {
    ITER2(g, 0, 1, 1, 1);
    ITER2(g + 1, 1, 1, 1, 1);
  }
  ITER2(NTILE - 2, 0, 1, 0, 2);
  ITER2(NTILE - 1, 1, 0, 0, 0);

  // ---- R12 epilogue: LDS-staged, 128B-contiguous stores ----
  // C/D frag layout: col = l15, row = l4*4+r. Stage each 64-row half of
  // the wave tile into epi[64][72] (144B rows, 16B-aligned), then store
  // 8 rows x 128B per iteration (8 lanes cover one row's 64 cols).
  short* epi = lds + wave * 4608;        // 64*72 shorts per wave
  const int col0 = bn * 256 + wn * 64;
  const int row0 = bm * BM + wm * (BM / 2);
  const int rg = lane >> 3, sg = lane & 7;
  float bb[4];
#pragma unroll
  for (int nt = 0; nt < 4; nt++)
    bb[nt] = BIAS ? bias[col0 + nt * 16 + l15] : 0.f;
#pragma unroll
  for (int h = 0; h < BMT; h++) {
#pragma unroll
    for (int m2 = 0; m2 < 4; m2++) {
#pragma unroll
      for (int nt = 0; nt < 4; nt++) {
#pragma unroll
        for (int r = 0; r < 4; r++) {
          float v = acc[h * 4 + m2][nt][r] + bb[nt];
          if (RELU) v = v > 0.f ? v : 0.f;
          epi[(m2 * 16 + l4 * 4 + r) * 72 + nt * 16 + l15] = f2bf(v);
        }
      }
    }
    FENCE;   // wave-local LDS: in-order DS pipe + compiler waits suffice
#pragma unroll
    for (int it = 0; it < 8; it++) {
      const int rl = it * 8 + rg;
      bf16x8 vv = *(const bf16x8*)(epi + rl * 72 + sg * 8);
      *(bf16x8*)(C + (long)(row0 + h * 64 + rl) * ldc + col0 + sg * 8) = vv;
    }
    FENCE;
  }
}

// ---------------- merged small GEMMs: qkh (blocks 0..63) + wf (64..127) ----
__global__ void __launch_bounds__(256) gemm_small(
    const short* __restrict__ in_bf, const short* __restrict__ wqk,
    short* __restrict__ qkh,
    const short* __restrict__ wo, const short* __restrict__ wvT,
    short* __restrict__ wf) {
  const short* A; const short* Bm; short* C;
  int ldc, bn, bm;
  const int bid = blockIdx.x;
  if (bid < 64) { A = in_bf; Bm = wqk; C = qkh; ldc = 128; bn = 0; bm = bid; }
  else { A = wo; Bm = wvT; C = wf; ldc = 1024; int b2 = bid - 64; bn = b2 & 7; bm = b2 >> 3; }
  const int lda = 1024, ldb = 1024, K = 1024;

  const short* Ab = A + (long)bm * 128 * lda;
  const short* Bb = Bm + (long)bn * 128 * ldb;

  __shared__ short lA[128 * 64];
  __shared__ short lB[128 * 64];

  const int tid = threadIdx.x;
  const int lane = tid & 63;
  const int wave = tid >> 6;
  const int wr = wave >> 1, wc = wave & 1;

  f32x4 acc[4][4];
#pragma unroll
  for (int i = 0; i < 4; i++)
#pragma unroll
    for (int j = 0; j < 4; j++) acc[i][j] = (f32x4){0.f, 0.f, 0.f, 0.f};

  for (int k0 = 0; k0 < K; k0 += 64) {
    __syncthreads();
#pragma unroll
    for (int i = 0; i < 4; i++) {
      int c = i * 256 + tid;
      int row = c >> 3;
      int col = (c & 7) * 8;
      gload_lds16(Ab + (long)row * lda + k0 + col, &lA[c * 8]);
      gload_lds16(Bb + (long)row * ldb + k0 + col, &lB[c * 8]);
    }
    __syncthreads();

#pragma unroll
    for (int ks = 0; ks < 2; ks++) {
      bf16x8 af[4], bfr[4];
#pragma unroll
      for (int t = 0; t < 4; t++) {
        af[t]  = *(const bf16x8*)&lA[(wr * 64 + t * 16 + (lane & 15)) * 64 + ks * 32 + (lane >> 4) * 8];
        bfr[t] = *(const bf16x8*)&lB[(wc * 64 + t * 16 + (lane & 15)) * 64 + ks * 32 + (lane >> 4) * 8];
      }
#pragma unroll
      for (int mt = 0; mt < 4; mt++)
#pragma unroll
        for (int nt = 0; nt < 4; nt++)
          acc[mt][nt] = __builtin_amdgcn_mfma_f32_16x16x32_bf16(af[mt], bfr[nt], acc[mt][nt], 0, 0, 0);
    }
  }

  const int col0 = bn * 128 + wc * 64;
  const int row0 = bm * 128 + wr * 64;
#pragma unroll
  for (int mt = 0; mt < 4; mt++) {
#pragma unroll
    for (int nt = 0; nt < 4; nt++) {
      int col = col0 + nt * 16 + (lane & 15);
      int rbase = row0 + mt * 16 + (lane >> 4) * 4;
#pragma unroll
      for (int r = 0; r < 4; r++)
        C[(long)(rbase + r) * ldc + col] = f2bf(acc[mt][nt][r]);
    }
  }
}

// =====================================================================
// Fused scores + softmax (+ /H), single-pass, S in registers.
// =====================================================================
__global__ void __launch_bounds__(512) fused_attn(
    const short* __restrict__ qkh, float* __restrict__ attn) {
  const int tid = threadIdx.x;
  const int lane = tid & 63;
  const int wave = tid >> 6;       // 0..7 (kv-eighth)
  const int l15 = lane & 15, l4 = lane >> 4;
  const int b = blockIdx.y;
  const int q0 = blockIdx.x * 16;
  const long base = (long)b * 2048;

  bf16x8 qf[2];
#pragma unroll
  for (int ks = 0; ks < 2; ks++)
    qf[ks] = *(const bf16x8*)&qkh[(base + q0 + l15) * 128 + ks * 32 + l4 * 8];

  const short* kb = qkh + (base + (long)wave * 256) * 128 + 64;

  f32x4 s[16];
#pragma unroll
  for (int kt = 0; kt < 16; kt++) {
    bf16x8 kf0 = *(const bf16x8*)&kb[(kt * 16 + l15) * 128 + l4 * 8];
    bf16x8 kf1 = *(const bf16x8*)&kb[(kt * 16 + l15) * 128 + 32 + l4 * 8];
    f32x4 a = (f32x4){0.f, 0.f, 0.f, 0.f};
    a = __builtin_amdgcn_mfma_f32_16x16x32_bf16(kf0, qf[0], a, 0, 0, 0);
    a = __builtin_amdgcn_mfma_f32_16x16x32_bf16(kf1, qf[1], a, 0, 0, 0);
    s[kt] = a;
  }

  float m = -1e30f;
#pragma unroll
  for (int kt = 0; kt < 16; kt++)
    m = fmaxf(m, fmaxf(fmaxf(s[kt][0], s[kt][1]), fmaxf(s[kt][2], s[kt][3])));
#pragma unroll
  for (int o = 16; o <= 32; o <<= 1) m = fmaxf(m, __shfl_xor(m, o, 64));

  float ss = 0.f;
#pragma unroll
  for (int kt = 0; kt < 16; kt++) {
    f32x4 e;
#pragma unroll
    for (int r = 0; r < 4; r++) e[r] = __expf(s[kt][r] - m);
    s[kt] = e;
    ss += (e[0] + e[1]) + (e[2] + e[3]);
  }
#pragma unroll
  for (int o = 16; o <= 32; o <<= 1) ss += __shfl_xor(ss, o, 64);

  __shared__ float lm[8][16], lsm[8][16];
  if (lane < 16) { lm[wave][l15] = m; lsm[wave][l15] = ss; }
  __syncthreads();
  float M = -1e30f;
#pragma unroll
  for (int w2 = 0; w2 < 8; w2++) M = fmaxf(M, lm[w2][l15]);
  float S = 0.f;
#pragma unroll
  for (int w2 = 0; w2 < 8; w2++) S += lsm[w2][l15] * __expf(lm[w2][l15] - M);
  const float f = __expf(m - M) / (S * 16.0f);   // includes the /H

  float* attb = attn + (base + q0 + l15) * 2048 + wave * 256 + l4 * 4;
#pragma unroll
  for (int kt = 0; kt < 16; kt++) {
    f32x4 p;
#pragma unroll
    for (int r = 0; r < 4; r++) p[r] = s[kt][r] * f;
    *(f32x4*)(attb + kt * 16) = p;
  }
}

// ---------------- fused residual + LayerNorm (f32 out) ----------------
__device__ __forceinline__ float wave_sum(float v) {
#pragma unroll
  for (int o = 32; o > 0; o >>= 1) v += __shfl_xor(v, o, 64);
  return v;
}

__global__ void __launch_bounds__(256) ln_fuse(
    const short* __restrict__ ctx, const short* __restrict__ ffn,
    const float* __restrict__ g, const float* __restrict__ bta,
    float* __restrict__ out) {
  const int tid = threadIdx.x;
  long base = (long)blockIdx.x * 1024 + tid * 4;
  short4 c4 = *(const short4*)(ctx + base);
  short4 f4 = *(const short4*)(ffn + base);
  float x0 = bf2f(c4.x) + bf2f(f4.x);
  float x1 = bf2f(c4.y) + bf2f(f4.y);
  float x2 = bf2f(c4.z) + bf2f(f4.z);
  float x3 = bf2f(c4.w) + bf2f(f4.w);

  float s = (x0 + x1) + (x2 + x3);
  float q = (x0 * x0 + x1 * x1) + (x2 * x2 + x3 * x3);
  __shared__ float rs[4], rq[4];
  s = wave_sum(s);
  q = wave_sum(q);
  if ((tid & 63) == 0) { rs[tid >> 6] = s; rq[tid >> 6] = q; }
  __syncthreads();
  float S = rs[0] + rs[1] + rs[2] + rs[3];
  float Q = rq[0] + rq[1] + rq[2] + rq[3];
  float mu = S * (1.0f / 1024.0f);
  float var = Q * (1.0f / 1024.0f) - mu * mu;
  float inv = rsqrtf(var + 1e-5f);

  float4 g4 = *(const float4*)(g + tid * 4);
  float4 b4 = *(const float4*)(bta + tid * 4);
  float4 o;
  o.x = (x0 - mu) * inv * g4.x + b4.x;
  o.y = (x1 - mu) * inv * g4.y + b4.y;
  o.z = (x2 - mu) * inv * g4.z + b4.z;
  o.w = (x3 - mu) * inv * g4.w + b4.w;
  *(float4*)(out + base) = o;
}

// ---------------- launch ----------------
extern "C" void kernel_launch(void* const* d_in, const int* in_sizes, int n_in,
                              void* d_out, int out_size, void* d_ws, size_t ws_size,
                              hipStream_t stream) {
  const float* inputs = (const float*)d_in[0];
  const float* Wq = (const float*)d_in[1];
  const float* Wk = (const float*)d_in[2];
  const float* Wv = (const float*)d_in[3];
  const float* Wo = (const float*)d_in[4];
  const float* W1 = (const float*)d_in[5];
  const float* b1 = (const float*)d_in[6];
  const float* W2 = (const float*)d_in[7];
  const float* b2 = (const float*)d_in[8];
  const float* ln_g = (const float*)d_in[9];
  const float* ln_b = (const float*)d_in[10];

  char* w = (char*)d_ws;
  short* in_bf = (short*)w;  w += (long)MTOK * D_ * 2;
  short* wqk   = (short*)w;  w += 128L * D_ * 2;
  short* wv    = (short*)w;  w += (long)D_ * D_ * 2;
  short* wo    = (short*)w;  w += (long)D_ * D_ * 2;
  short* w1    = (short*)w;  w += (long)F_ * D_ * 2;
  short* w2    = (short*)w;  w += (long)D_ * F_ * 2;
  short* qkh   = (short*)w;  w += (long)MTOK * 128 * 2;
  short* wvT   = (short*)w;  w += (long)D_ * D_ * 2;   // Wv^T (bf16)
  short* wf    = (short*)w;  w += (long)D_ * D_ * 2;   // Wf = Wo @ Wv (bf16)
  short* ctxbf = (short*)w;  w += (long)MTOK * D_ * 2;
  short* hbf   = (short*)w;  w += (long)MTOK * F_ * 2;
  short* ffnbf = (short*)w;  w += (long)MTOK * D_ * 2;

  float* out  = (float*)d_out;                 // [8192][1024]
  float* attn = out + (long)MTOK * D_;         // [4][2048][2048]

  // all conversions in one launch (wq slice pre-scaled by DH^-0.5)
  convert_all<<<dim3(18560), 256, 0, stream>>>(
      Wq, Wk, Wv, Wo, W1, W2, inputs, wqk, wv, wo, w1, w2, in_bf);

  // Wv^T, then merged small GEMMs: qkh = in @ wqk^T  and  wf = Wo @ Wv
  transpose_bf16_1k<<<dim3(16, 16), 256, 0, stream>>>(wv, wvT);
  gemm_small<<<dim3(128), 256, 0, stream>>>(in_bf, wqk, qkh, wo, wvT, wf);

  // attn = softmax(qH @ kH^T)/H  — single-pass fused
  fused_attn<<<dim3(128, 4), 512, 0, stream>>>(qkh, attn);
  // context = inputs @ Wf^T  (M=8192, N=1024, K=1024)
  gemm8p<1, false, false><<<dim3(4, 64), 512, 0, stream>>>(
      in_bf, D_, wf, D_, ctxbf, D_, nullptr, D_);
  // h = relu(ctx @ W1^T + b1) (M=8192, N=4096, K=1024)
  gemm8p<2, true, true><<<dim3(16, 32), 512, 0, stream>>>(
      ctxbf, D_, w1, D_, hbf, F_, b1, D_);
  // ffn = h @ W2^T + b2       (M=8192, N=1024, K=4096)
  gemm8p<1, true, false><<<dim3(4, 64), 512, 0, stream>>>(
      hbf, F_, w2, F_, ffnbf, D_, b2, F_);
  // out = LN(ctx + ffn)
  ln_fuse<<<dim3(MTOK), 256, 0, stream>>>(ctxbf, ffnbf, ln_g, ln_b, out);
}